// Round 1
// baseline (798.878 us; speedup 1.0000x reference)
//
#include <hip/hip_runtime.h>
#include <math.h>

// RPN forward: conv3x3+relu -> 1x1 heads + softmax + deparameterize -> greedy NMS top-5.
// All fp32, replicating reference numerics (exact pow2 divides, expf, fmaf).

#define HH 32
#define WW 32
#define NPIX 1024          // 32*32
#define CIN 512
#define COUT 512
#define NA 9
#define NBOX (NPIX * NA)   // 9216
#define NMS_THR 0.7f
#define NOUT 5

// ---------------------------------------------------------------------------
// Kernel 1: 3x3 conv, 512->512, pad 1, + bias + ReLU.
// Tile: 8 oc x 128 px (4 rows x 32 cols). 512 blocks x 128 threads.
// Weights via uniform s_load (SGPR operand to v_fma). Activations via LDS.
// Output stored transposed: feats_t[pixel][oc] for coalesced head reads.
// ---------------------------------------------------------------------------
__global__ __launch_bounds__(128) void conv3x3_relu_kernel(
    const float* __restrict__ x, const float* __restrict__ w,
    const float* __restrict__ b, float* __restrict__ feats_t)
{
    // XCD swizzle: blocks sharing an oc-tile's weights land on one XCD.
    int bid = blockIdx.x;          // 0..511
    int xcd = bid & 7;
    int g   = bid >> 3;            // 0..63
    int oct = xcd * 8 + (g & 7);   // 0..63  (oc tile)
    int pxt = g >> 3;              // 0..7   (pixel-row tile)
    int ocb = oct * 8;
    int r0  = pxt * 4;

    int tid = threadIdx.x;         // 0..127
    int r = tid >> 5;              // 0..3 (row within tile)
    int c = tid & 31;              // 0..31 (col)

    __shared__ float xs[16][6][36];   // [ic][row r0-1..r0+4][col -1..34]  13.8 KB

    float acc[8];
#pragma unroll
    for (int o = 0; o < 8; ++o) acc[o] = 0.f;

    for (int icb = 0; icb < CIN; icb += 16) {
        __syncthreads();
        // stage x[icb..icb+15][r0-1..r0+4][-1..34], zero-padded
        for (int i = tid; i < 16 * 6 * 36; i += 128) {
            int ic  = i / 216;
            int rem = i % 216;
            int ry  = rem / 36;
            int cx  = rem % 36;
            int gr  = r0 - 1 + ry;
            int gc  = cx - 1;
            float v = 0.f;
            if (gr >= 0 && gr < HH && gc >= 0 && gc < WW)
                v = x[(size_t)(icb + ic) * NPIX + gr * WW + gc];
            xs[ic][ry][cx] = v;
        }
        __syncthreads();

#pragma unroll 4
        for (int ic = 0; ic < 16; ++ic) {
            const float* wr0 = w + ((size_t)ocb * CIN + (size_t)(icb + ic)) * 9;
#pragma unroll
            for (int ky = 0; ky < 3; ++ky) {
                float x0 = xs[ic][r + ky][c + 0];
                float x1 = xs[ic][r + ky][c + 1];
                float x2 = xs[ic][r + ky][c + 2];
#pragma unroll
                for (int o = 0; o < 8; ++o) {
                    const float* wr = wr0 + (size_t)o * (CIN * 9) + ky * 3;  // uniform -> s_load
                    acc[o] = fmaf(wr[0], x0, acc[o]);
                    acc[o] = fmaf(wr[1], x1, acc[o]);
                    acc[o] = fmaf(wr[2], x2, acc[o]);
                }
            }
        }
    }

    int p = (r0 + r) * WW + c;
    float4 v0, v1;
    float* vp0 = (float*)&v0;
    float* vp1 = (float*)&v1;
#pragma unroll
    for (int o = 0; o < 4; ++o) vp0[o] = fmaxf(acc[o] + b[ocb + o], 0.f);
#pragma unroll
    for (int o = 0; o < 4; ++o) vp1[o] = fmaxf(acc[4 + o] + b[ocb + 4 + o], 0.f);
    float4* outp = (float4*)(feats_t + (size_t)p * COUT + ocb);
    outp[0] = v0;
    outp[1] = v1;
}

// ---------------------------------------------------------------------------
// Kernel 2: per-pixel 1x1 heads (18 cls + 36 reg dots over 512), softmax over
// channel pairs, anchor construction + deparameterize. One block per pixel.
// ---------------------------------------------------------------------------
__global__ __launch_bounds__(64) void head_kernel(
    const float* __restrict__ feats_t,
    const float* __restrict__ w_cls, const float* __restrict__ b_cls,
    const float* __restrict__ w_reg, const float* __restrict__ b_reg,
    const float* __restrict__ anchors_wh,
    float* __restrict__ boxes, float* __restrict__ probs,
    float* __restrict__ scores)
{
    int p = blockIdx.x;       // 0..1023
    int tid = threadIdx.x;    // 0..63

    __shared__ float fs[CIN];
    __shared__ float dots[54];

    const float4* fr  = (const float4*)(feats_t + (size_t)p * CIN);
    float4* fs4 = (float4*)fs;
    for (int i = tid; i < CIN / 4; i += 64) fs4[i] = fr[i];
    __syncthreads();

    if (tid < 54) {
        const float* wr = (tid < 18) ? (w_cls + (size_t)tid * CIN)
                                     : (w_reg + (size_t)(tid - 18) * CIN);
        float bias = (tid < 18) ? b_cls[tid] : b_reg[tid - 18];
        const float4* w4 = (const float4*)wr;
        float s0 = 0.f, s1 = 0.f, s2 = 0.f, s3 = 0.f;
#pragma unroll 8
        for (int i = 0; i < CIN / 4; ++i) {
            float4 f = fs4[i];
            float4 wv = w4[i];
            s0 = fmaf(f.x, wv.x, s0);
            s1 = fmaf(f.y, wv.y, s1);
            s2 = fmaf(f.z, wv.z, s2);
            s3 = fmaf(f.w, wv.w, s3);
        }
        dots[tid] = ((s0 + s1) + (s2 + s3)) + bias;
    }
    __syncthreads();

    if (tid < NA) {
        int a = tid;
        // softmax over (c0, c1)
        float c0 = dots[2 * a], c1 = dots[2 * a + 1];
        float m  = fmaxf(c0, c1);
        float e0 = expf(c0 - m), e1 = expf(c1 - m);
        float inv = 1.f / (e0 + e1);
        float p0 = e0 * inv, p1 = e1 * inv;

        // anchor (ih over h-axis pairs with box x; iw with y) per reference
        int ih = p >> 5, iw = p & 31;
        float wa = anchors_wh[2 * a + 0];
        float ha = anchors_wh[2 * a + 1];
        float fih = (float)ih, fiw = (float)iw;
        float ax1 = (-(wa / 2.0f) + fih) / 32.0f;
        float ay1 = (-(ha / 2.0f) + fiw) / 32.0f;
        float ax2 = ((wa / 2.0f) + fih) / 32.0f;
        float ay2 = ((ha / 2.0f) + fiw) / 32.0f;
        float wab = ax2 - ax1;
        float hab = ay2 - ay1;
        float xa  = (ax1 + ax2) * 0.5f;
        float ya  = (ay1 + ay2) * 0.5f;

        float rg0 = dots[18 + 4 * a + 0];
        float rg1 = dots[18 + 4 * a + 1];
        float rg2 = dots[18 + 4 * a + 2];
        float rg3 = dots[18 + 4 * a + 3];
        float xc = rg0 * wab + xa;
        float yc = rg1 * hab + ya;
        float bw = expf(rg2) * wab;
        float bh = expf(rg3) * hab;

        int idx = p * NA + a;
        float4 bx;
        bx.x = xc - bw / 2.0f;
        bx.y = yc - bh / 2.0f;
        bx.z = xc + bw / 2.0f;
        bx.w = yc + bh / 2.0f;
        ((float4*)boxes)[idx] = bx;
        probs[idx * 2 + 0] = p0;
        probs[idx * 2 + 1] = p1;
        scores[idx] = p0;
    }
}

// ---------------------------------------------------------------------------
// Kernel 3: greedy NMS, 5 picks. Single block, 1024 threads. Equivalent to
// reference's sorted-scan NMS (stable argsort ties -> min index tiebreak).
// ---------------------------------------------------------------------------
__global__ __launch_bounds__(1024) void nms_kernel(
    const float* __restrict__ boxes, const float* __restrict__ probs,
    const float* __restrict__ scores, float* __restrict__ out)
{
    __shared__ float sc[NBOX];     // 36 KB, -inf = suppressed
    __shared__ float redv[16];
    __shared__ int   redi[16];
    __shared__ int   keep[NOUT];
    __shared__ float bbox[4];

    int tid = threadIdx.x;
    for (int i = tid; i < NBOX; i += 1024) sc[i] = scores[i];
    __syncthreads();

    for (int k = 0; k < NOUT; ++k) {
        // per-thread argmax (ties -> min index)
        float bv = -1e30f;
        int   bi = NBOX;
        for (int i = tid; i < NBOX; i += 1024) {
            float v = sc[i];
            if (v > bv || (v == bv && i < bi)) { bv = v; bi = i; }
        }
        // wave64 reduction
#pragma unroll
        for (int off = 32; off > 0; off >>= 1) {
            float ov = __shfl_down(bv, off);
            int   oi = __shfl_down(bi, off);
            if (ov > bv || (ov == bv && oi < bi)) { bv = ov; bi = oi; }
        }
        if ((tid & 63) == 0) { redv[tid >> 6] = bv; redi[tid >> 6] = bi; }
        __syncthreads();
        if (tid == 0) {
            float fv = redv[0]; int fi = redi[0];
#pragma unroll
            for (int wv = 1; wv < 16; ++wv) {
                if (redv[wv] > fv || (redv[wv] == fv && redi[wv] < fi)) {
                    fv = redv[wv]; fi = redi[wv];
                }
            }
            keep[k] = fi;
            bbox[0] = boxes[(size_t)fi * 4 + 0];
            bbox[1] = boxes[(size_t)fi * 4 + 1];
            bbox[2] = boxes[(size_t)fi * 4 + 2];
            bbox[3] = boxes[(size_t)fi * 4 + 3];
        }
        __syncthreads();
        float bx0 = bbox[0], bx1 = bbox[1], bx2 = bbox[2], bx3 = bbox[3];
        float aa = (bx2 - bx0) * (bx3 - bx1);
        for (int i = tid; i < NBOX; i += 1024) {
            if (sc[i] > -1e29f) {
                float4 bb = ((const float4*)boxes)[i];
                float ltx = fmaxf(bx0, bb.x);
                float lty = fmaxf(bx1, bb.y);
                float rbx = fminf(bx2, bb.z);
                float rby = fminf(bx3, bb.w);
                float iw2 = fmaxf(rbx - ltx, 0.f);
                float ih2 = fmaxf(rby - lty, 0.f);
                float inter = iw2 * ih2;
                float ab = (bb.z - bb.x) * (bb.w - bb.y);
                float iou = inter / (aa + ab - inter);
                if (iou > NMS_THR) sc[i] = -1e30f;  // includes the pick itself (iou=1)
            }
        }
        __syncthreads();
    }

    if (tid < NOUT) {
        int ki = keep[tid];
        out[tid * 2 + 0] = probs[(size_t)ki * 2 + 0];
        out[tid * 2 + 1] = probs[(size_t)ki * 2 + 1];
        out[2 * NOUT + tid * 4 + 0] = boxes[(size_t)ki * 4 + 0];
        out[2 * NOUT + tid * 4 + 1] = boxes[(size_t)ki * 4 + 1];
        out[2 * NOUT + tid * 4 + 2] = boxes[(size_t)ki * 4 + 2];
        out[2 * NOUT + tid * 4 + 3] = boxes[(size_t)ki * 4 + 3];
    }
}

// ---------------------------------------------------------------------------
extern "C" void kernel_launch(void* const* d_in, const int* in_sizes, int n_in,
                              void* d_out, int out_size, void* d_ws, size_t ws_size,
                              hipStream_t stream)
{
    const float* x          = (const float*)d_in[0];
    const float* w_win      = (const float*)d_in[1];
    const float* b_win      = (const float*)d_in[2];
    const float* w_cls      = (const float*)d_in[3];
    const float* b_cls      = (const float*)d_in[4];
    const float* w_reg      = (const float*)d_in[5];
    const float* b_reg      = (const float*)d_in[6];
    const float* anchors_wh = (const float*)d_in[7];

    float* ws     = (float*)d_ws;
    float* feats  = ws;                         // 524288 floats (2 MB)
    float* boxes  = feats + (size_t)NPIX * COUT; // 36864
    float* probs  = boxes + (size_t)NBOX * 4;    // 18432
    float* scores = probs + (size_t)NBOX * 2;    // 9216

    conv3x3_relu_kernel<<<512, 128, 0, stream>>>(x, w_win, b_win, feats);
    head_kernel<<<NPIX, 64, 0, stream>>>(feats, w_cls, b_cls, w_reg, b_reg,
                                         anchors_wh, boxes, probs, scores);
    nms_kernel<<<1, 1024, 0, stream>>>(boxes, probs, scores, (float*)d_out);
}

// Round 3
// 172.450 us; speedup vs baseline: 4.6325x; 4.6325x over previous
//
#include <hip/hip_runtime.h>
#include <math.h>

// RPN forward: conv3x3 as MFMA implicit-GEMM (fp16 hi/lo split, 3-pass, fp32-like
// accuracy) -> 1x1 heads + softmax + deparameterize -> greedy NMS top-5.

#define HH 32
#define WW 32
#define NPIX 1024
#define CIN 512
#define COUT 512
#define NA 9
#define NBOX (NPIX * NA)
#define NMS_THR 0.7f
#define NOUT 5

typedef _Float16 half8 __attribute__((ext_vector_type(8)));
typedef float f32x4 __attribute__((ext_vector_type(4)));

#define GLOAD16(src, dst) \
    __builtin_amdgcn_global_load_lds((const __attribute__((address_space(1))) void*)(src), \
                                     (__attribute__((address_space(3))) void*)(dst), 16, 0, 0)

// ---------------------------------------------------------------------------
// prep: fused weight + activation preprocessing.
//  blocks 0..1023   : w OIHW [512][512][3][3] -> wt[q][oc][ic] fp16 hi/lo
//  blocks 1024..1151: x [512][32][32] -> zero-padded pixel-major fp16 hi/lo
//                     xp[34*34][512] (interior, via LDS transpose)
//  blocks 1152..1187: zero the 132 border pixel-rows of xp (ws is re-poisoned
//                     to 0xAA before every timed call -> must rewrite borders)
// ---------------------------------------------------------------------------
__global__ __launch_bounds__(256) void prep_kernel(
    const float* __restrict__ x, const float* __restrict__ w,
    _Float16* __restrict__ xp_hi, _Float16* __restrict__ xp_lo,
    _Float16* __restrict__ wt_hi, _Float16* __restrict__ wt_lo)
{
    int b = blockIdx.x;
    int tid = threadIdx.x;
    if (b < 1024) {
        int t = b * 256 + tid;                 // oc*512 + ic, 0..262143
#pragma unroll
        for (int q = 0; q < 9; ++q) {
            float v = w[(size_t)t * 9 + q];
            _Float16 hi = (_Float16)v;
            _Float16 lo = (_Float16)(v - (float)hi);
            wt_hi[(size_t)q * 262144 + t] = hi;
            wt_lo[(size_t)q * 262144 + t] = lo;
        }
    } else if (b < 1152) {
        __shared__ float xs[64][65];
        int bb = b - 1024;                     // 0..127
        int ic0 = (bb & 7) * 64;
        int pix0 = (bb >> 3) * 64;
#pragma unroll
        for (int r = 0; r < 16; ++r) {
            int i = r * 4 + (tid >> 6);        // ic
            int j = tid & 63;                  // pixel
            xs[i][j] = x[(size_t)(ic0 + i) * NPIX + pix0 + j];
        }
        __syncthreads();
#pragma unroll
        for (int rr = 0; rr < 16; ++rr) {
            int j = rr * 4 + (tid >> 6);       // pixel
            int i = tid & 63;                  // ic
            float v = xs[i][j];
            int p = pix0 + j;
            int row = ((p >> 5) + 1) * 34 + (p & 31) + 1;
            _Float16 hi = (_Float16)v;
            _Float16 lo = (_Float16)(v - (float)hi);
            xp_hi[(size_t)row * 512 + ic0 + i] = hi;
            xp_lo[(size_t)row * 512 + ic0 + i] = lo;
        }
    } else {
        int base = (b - 1152) * 256 + tid;     // 0..9215
        for (int e = base; e < 132 * 512; e += 36 * 256) {
            int br = e >> 9;
            int ic = e & 511;
            int row;
            if (br < 34) row = br;                           // top padded row
            else if (br < 68) row = 33 * 34 + (br - 34);     // bottom padded row
            else { int c2 = br - 68; row = (1 + (c2 >> 1)) * 34 + (c2 & 1) * 33; }
            xp_hi[(size_t)row * 512 + ic] = (_Float16)0.f;
            xp_lo[(size_t)row * 512 + ic] = (_Float16)0.f;
        }
    }
}

// ---------------------------------------------------------------------------
// conv_gemm: implicit-GEMM conv3x3 via v_mfma_f32_16x16x32_f16.
// M=1024 px, N=512 oc, K=4608 (q-major, ic inner). BM=32 (one image row),
// BN=64, BK=64. 256 blocks x 256 thr (4 waves 2x2; wave tile 16x32).
// fp16 split, 3 passes: acc = Ah*Bh + (Ah*Bl + Al*Bh); Al*Bl (~2^-22) dropped.
// LDS XOR-swizzled ((row&7)<<4 on each 128B row) via pre-swizzled global src
// (global_load_lds writes linearly: uniform base + lane*16). Double-buffered.
// Epilogue fuses bias+ReLU, writes feats[pix][oc].
// ---------------------------------------------------------------------------
#define BUFSZ 24576   // A_hi 4K | A_lo 4K | B_hi 8K | B_lo 8K
__global__ __launch_bounds__(256) void conv_gemm_kernel(
    const _Float16* __restrict__ xp_hi, const _Float16* __restrict__ xp_lo,
    const _Float16* __restrict__ wt_hi, const _Float16* __restrict__ wt_lo,
    const float* __restrict__ bias, float* __restrict__ feats)
{
    __shared__ __align__(16) char smem[2 * BUFSZ];
    int bid = blockIdx.x;
    int nt = bid & 7;            // oc tile: bid%8 -> all blocks of one panel on one XCD
    int ph = bid >> 3;           // 0..31 image row
    int oc0 = nt * 64;

    int tid = threadIdx.x;
    int wave = tid >> 6, lane = tid & 63;

    // staging: linear LDS dest row -> pre-swizzled source column
    int sRow = wave * 8 + (lane >> 3);                          // 0..31
    int khalf = ((((lane & 7) * 16) ^ ((sRow & 7) << 4)) >> 1); // element offset
    const _Float16* srcAh = xp_hi + (size_t)(ph * 34 + sRow) * 512 + khalf;
    const _Float16* srcAl = xp_lo + (size_t)(ph * 34 + sRow) * 512 + khalf;
    const _Float16* srcBh = wt_hi + (size_t)(oc0 + sRow) * 512 + khalf;
    const _Float16* srcBl = wt_lo + (size_t)(oc0 + sRow) * 512 + khalf;
    int ldsW = wave * 1024;      // per-wave dest base (+lane*16 implicit)

#define STAGE(kb, bufb) do {                                                   \
        int q_ = (kb) >> 3, icc_ = (kb) & 7;                                   \
        int qy_ = (q_ * 11) >> 5; int qx_ = q_ - qy_ * 3;                      \
        size_t ao_ = (size_t)(qy_ * 34 + qx_) * 512 + icc_ * 64;               \
        size_t bo_ = (size_t)q_ * 262144 + icc_ * 64;                          \
        char* bb_ = smem + (bufb);                                             \
        GLOAD16(srcAh + ao_, bb_ + 0     + ldsW);                              \
        GLOAD16(srcAl + ao_, bb_ + 4096  + ldsW);                              \
        GLOAD16(srcBh + bo_, bb_ + 8192  + ldsW);                              \
        GLOAD16(srcBh + bo_ + 16384, bb_ + 12288 + ldsW);                      \
        GLOAD16(srcBl + bo_, bb_ + 16384 + ldsW);                              \
        GLOAD16(srcBl + bo_ + 16384, bb_ + 20480 + ldsW);                      \
    } while (0)

    // compute-side fragment addressing
    int wm = wave >> 1, wn = wave & 1;
    int ml = lane & 15, kq = lane >> 4;
    int swz = (ml & 7) << 4;
    int aoff  = (wm * 16 + ml) * 128 + ((kq * 16) ^ swz);
    int boff0 = (wn * 32 + ml) * 128 + ((kq * 16) ^ swz);
    int boff1 = boff0 + 2048;    // +16 oc rows

    f32x4 hh[2], co[2];
#pragma unroll
    for (int n = 0; n < 2; ++n) { hh[n] = (f32x4)0.f; co[n] = (f32x4)0.f; }

#define COMPUTE(bufb) do {                                                     \
        const char* bb_ = smem + (bufb);                                       \
        _Pragma("unroll")                                                      \
        for (int ks = 0; ks < 2; ++ks) {                                       \
            int kx_ = ks * 64;                                                 \
            half8 ah  = *(const half8*)(bb_ + 0     + (aoff  ^ kx_));          \
            half8 al  = *(const half8*)(bb_ + 4096  + (aoff  ^ kx_));          \
            half8 bh0 = *(const half8*)(bb_ + 8192  + (boff0 ^ kx_));          \
            half8 bh1 = *(const half8*)(bb_ + 8192  + (boff1 ^ kx_));          \
            half8 bl0 = *(const half8*)(bb_ + 16384 + (boff0 ^ kx_));          \
            half8 bl1 = *(const half8*)(bb_ + 16384 + (boff1 ^ kx_));          \
            hh[0] = __builtin_amdgcn_mfma_f32_16x16x32_f16(ah, bh0, hh[0], 0, 0, 0); \
            hh[1] = __builtin_amdgcn_mfma_f32_16x16x32_f16(ah, bh1, hh[1], 0, 0, 0); \
            co[0] = __builtin_amdgcn_mfma_f32_16x16x32_f16(ah, bl0, co[0], 0, 0, 0); \
            co[1] = __builtin_amdgcn_mfma_f32_16x16x32_f16(ah, bl1, co[1], 0, 0, 0); \
            co[0] = __builtin_amdgcn_mfma_f32_16x16x32_f16(al, bh0, co[0], 0, 0, 0); \
            co[1] = __builtin_amdgcn_mfma_f32_16x16x32_f16(al, bh1, co[1], 0, 0, 0); \
        }                                                                      \
    } while (0)

    STAGE(0, 0);
    __syncthreads();
    int buf = 0;
    for (int kb = 0; kb < 72; ++kb) {
        if (kb < 71) STAGE(kb + 1, (buf ^ 1) * BUFSZ);
        COMPUTE(buf * BUFSZ);
        __syncthreads();
        buf ^= 1;
    }

    // epilogue: C layout col=lane&15, row=(lane>>4)*4+j (m89-verified)
#pragma unroll
    for (int n = 0; n < 2; ++n) {
        int oc = oc0 + wn * 32 + n * 16 + ml;
        float bv = bias[oc];
#pragma unroll
        for (int j = 0; j < 4; ++j) {
            float v = hh[n][j] + co[n][j];
            v = fmaxf(v + bv, 0.f);
            int pw = wm * 16 + kq * 4 + j;
            feats[(size_t)(ph * 32 + pw) * 512 + oc] = v;
        }
    }
#undef STAGE
#undef COMPUTE
}

// ---------------------------------------------------------------------------
// head: per-pixel 1x1 heads (18 cls + 36 reg dots over 512), softmax pairs,
// anchor construct + deparameterize. One block per pixel.
// ---------------------------------------------------------------------------
__global__ __launch_bounds__(64) void head_kernel(
    const float* __restrict__ feats_t,
    const float* __restrict__ w_cls, const float* __restrict__ b_cls,
    const float* __restrict__ w_reg, const float* __restrict__ b_reg,
    const float* __restrict__ anchors_wh,
    float* __restrict__ boxes, float* __restrict__ probs)
{
    int p = blockIdx.x;
    int tid = threadIdx.x;

    __shared__ float fs[CIN];
    __shared__ float dots[54];

    const float4* fr = (const float4*)(feats_t + (size_t)p * CIN);
    float4* fs4 = (float4*)fs;
    for (int i = tid; i < CIN / 4; i += 64) fs4[i] = fr[i];
    __syncthreads();

    if (tid < 54) {
        const float* wr = (tid < 18) ? (w_cls + (size_t)tid * CIN)
                                     : (w_reg + (size_t)(tid - 18) * CIN);
        float bv = (tid < 18) ? b_cls[tid] : b_reg[tid - 18];
        const float4* w4 = (const float4*)wr;
        float s0 = 0.f, s1 = 0.f, s2 = 0.f, s3 = 0.f;
#pragma unroll 8
        for (int i = 0; i < CIN / 4; ++i) {
            float4 f = fs4[i];
            float4 wv = w4[i];
            s0 = fmaf(f.x, wv.x, s0);
            s1 = fmaf(f.y, wv.y, s1);
            s2 = fmaf(f.z, wv.z, s2);
            s3 = fmaf(f.w, wv.w, s3);
        }
        dots[tid] = ((s0 + s1) + (s2 + s3)) + bv;
    }
    __syncthreads();

    if (tid < NA) {
        int a = tid;
        float c0 = dots[2 * a], c1 = dots[2 * a + 1];
        float m = fmaxf(c0, c1);
        float e0 = expf(c0 - m), e1 = expf(c1 - m);
        float inv = 1.f / (e0 + e1);
        float p0 = e0 * inv, p1 = e1 * inv;

        int ih = p >> 5, iw = p & 31;        // ih pairs with box x (reference)
        float wa = anchors_wh[2 * a + 0];
        float ha = anchors_wh[2 * a + 1];
        float fih = (float)ih, fiw = (float)iw;
        float ax1 = (-(wa / 2.0f) + fih) / 32.0f;
        float ay1 = (-(ha / 2.0f) + fiw) / 32.0f;
        float ax2 = ((wa / 2.0f) + fih) / 32.0f;
        float ay2 = ((ha / 2.0f) + fiw) / 32.0f;
        float wab = ax2 - ax1;
        float hab = ay2 - ay1;
        float xa = (ax1 + ax2) * 0.5f;
        float ya = (ay1 + ay2) * 0.5f;

        float rg0 = dots[18 + 4 * a + 0];
        float rg1 = dots[18 + 4 * a + 1];
        float rg2 = dots[18 + 4 * a + 2];
        float rg3 = dots[18 + 4 * a + 3];
        float xc = rg0 * wab + xa;
        float yc = rg1 * hab + ya;
        float bw = expf(rg2) * wab;
        float bh = expf(rg3) * hab;

        int idx = p * NA + a;
        float4 bx;
        bx.x = xc - bw / 2.0f;
        bx.y = yc - bh / 2.0f;
        bx.z = xc + bw / 2.0f;
        bx.w = yc + bh / 2.0f;
        ((float4*)boxes)[idx] = bx;
        probs[idx * 2 + 0] = p0;
        probs[idx * 2 + 1] = p1;
    }
}

// ---------------------------------------------------------------------------
// nms: greedy top-5, equivalent to reference sorted-scan NMS (stable argsort
// ties -> min-index tiebreak). Scores = probs[2i].
// ---------------------------------------------------------------------------
__global__ __launch_bounds__(1024) void nms_kernel(
    const float* __restrict__ boxes, const float* __restrict__ probs,
    float* __restrict__ out)
{
    __shared__ float sc[NBOX];
    __shared__ float redv[16];
    __shared__ int   redi[16];
    __shared__ int   keep[NOUT];
    __shared__ float bbox[4];

    int tid = threadIdx.x;
    for (int i = tid; i < NBOX; i += 1024) sc[i] = probs[2 * i];
    __syncthreads();

    for (int k = 0; k < NOUT; ++k) {
        float bv = -1e30f;
        int   bi = NBOX;
        for (int i = tid; i < NBOX; i += 1024) {
            float v = sc[i];
            if (v > bv || (v == bv && i < bi)) { bv = v; bi = i; }
        }
#pragma unroll
        for (int off = 32; off > 0; off >>= 1) {
            float ov = __shfl_down(bv, off);
            int   oi = __shfl_down(bi, off);
            if (ov > bv || (ov == bv && oi < bi)) { bv = ov; bi = oi; }
        }
        if ((tid & 63) == 0) { redv[tid >> 6] = bv; redi[tid >> 6] = bi; }
        __syncthreads();
        if (tid == 0) {
            float fv = redv[0]; int fi = redi[0];
#pragma unroll
            for (int wv = 1; wv < 16; ++wv) {
                if (redv[wv] > fv || (redv[wv] == fv && redi[wv] < fi)) {
                    fv = redv[wv]; fi = redi[wv];
                }
            }
            keep[k] = fi;
            bbox[0] = boxes[(size_t)fi * 4 + 0];
            bbox[1] = boxes[(size_t)fi * 4 + 1];
            bbox[2] = boxes[(size_t)fi * 4 + 2];
            bbox[3] = boxes[(size_t)fi * 4 + 3];
        }
        __syncthreads();
        float bx0 = bbox[0], bx1 = bbox[1], bx2 = bbox[2], bx3 = bbox[3];
        float aa = (bx2 - bx0) * (bx3 - bx1);
        for (int i = tid; i < NBOX; i += 1024) {
            if (sc[i] > -1e29f) {
                float4 bb = ((const float4*)boxes)[i];
                float ltx = fmaxf(bx0, bb.x);
                float lty = fmaxf(bx1, bb.y);
                float rbx = fminf(bx2, bb.z);
                float rby = fminf(bx3, bb.w);
                float iw2 = fmaxf(rbx - ltx, 0.f);
                float ih2 = fmaxf(rby - lty, 0.f);
                float inter = iw2 * ih2;
                float ab = (bb.z - bb.x) * (bb.w - bb.y);
                float iou = inter / (aa + ab - inter);
                if (iou > NMS_THR) sc[i] = -1e30f;   // suppresses the pick too
            }
        }
        __syncthreads();
    }

    if (tid < NOUT) {
        int ki = keep[tid];
        out[tid * 2 + 0] = probs[(size_t)ki * 2 + 0];
        out[tid * 2 + 1] = probs[(size_t)ki * 2 + 1];
        out[2 * NOUT + tid * 4 + 0] = boxes[(size_t)ki * 4 + 0];
        out[2 * NOUT + tid * 4 + 1] = boxes[(size_t)ki * 4 + 1];
        out[2 * NOUT + tid * 4 + 2] = boxes[(size_t)ki * 4 + 2];
        out[2 * NOUT + tid * 4 + 3] = boxes[(size_t)ki * 4 + 3];
    }
}

// ---------------------------------------------------------------------------
extern "C" void kernel_launch(void* const* d_in, const int* in_sizes, int n_in,
                              void* d_out, int out_size, void* d_ws, size_t ws_size,
                              hipStream_t stream)
{
    const float* x          = (const float*)d_in[0];
    const float* w_win      = (const float*)d_in[1];
    const float* b_win      = (const float*)d_in[2];
    const float* w_cls      = (const float*)d_in[3];
    const float* b_cls      = (const float*)d_in[4];
    const float* w_reg      = (const float*)d_in[5];
    const float* b_reg      = (const float*)d_in[6];
    const float* anchors_wh = (const float*)d_in[7];

    char* wsb = (char*)d_ws;
    float*     feats  = (float*)(wsb);                    // 2,097,152 B
    float*     boxes  = (float*)(wsb + 2097152);          //   147,456 B
    float*     probs  = (float*)(wsb + 2244608);          //    73,728 B
    _Float16*  xp_hi  = (_Float16*)(wsb + 2318336);       // 1,183,744 B
    _Float16*  xp_lo  = (_Float16*)(wsb + 3502080);       // 1,183,744 B
    _Float16*  wt_hi  = (_Float16*)(wsb + 4685824);       // 4,718,592 B
    _Float16*  wt_lo  = (_Float16*)(wsb + 9404416);       // 4,718,592 B  (end ~13.5 MB)

    prep_kernel<<<1188, 256, 0, stream>>>(x, w_win, xp_hi, xp_lo, wt_hi, wt_lo);
    conv_gemm_kernel<<<256, 256, 0, stream>>>(xp_hi, xp_lo, wt_hi, wt_lo, b_win, feats);
    head_kernel<<<NPIX, 64, 0, stream>>>(feats, w_cls, b_cls, w_reg, b_reg,
                                         anchors_wh, boxes, probs);
    nms_kernel<<<1, 1024, 0, stream>>>(boxes, probs, (float*)d_out);
}

// Round 7
// 144.925 us; speedup vs baseline: 5.5123x; 1.1899x over previous
//
#include <hip/hip_runtime.h>
#include <math.h>

// RPN forward: conv3x3 as MFMA implicit-GEMM (fp16 hi/lo 3-pass split, fp32-like
// accuracy, split-K x2 for 2 blocks/CU) -> fused reduce+bias+relu+1x1 heads
// -> register-resident greedy NMS top-5.

#define HH 32
#define WW 32
#define NPIX 1024
#define CIN 512
#define COUT 512
#define NA 9
#define NBOX (NPIX * NA)
#define NMS_THR 0.7f
#define NOUT 5

typedef _Float16 half8 __attribute__((ext_vector_type(8)));
typedef float f32x4 __attribute__((ext_vector_type(4)));

#define GLOAD16(src, dst) \
    __builtin_amdgcn_global_load_lds((const __attribute__((address_space(1))) void*)(src), \
                                     (__attribute__((address_space(3))) void*)(dst), 16, 0, 0)

// ---------------------------------------------------------------------------
// prep: fused weight + activation preprocessing (R3-validated).
//  blocks 0..1023   : w OIHW -> wt[q][oc][ic] fp16 hi/lo
//  blocks 1024..1151: x -> zero-padded pixel-major fp16 hi/lo xp[34*34][512]
//  blocks 1152..1187: rewrite the 132 border pixel-rows (ws re-poisoned 0xAA)
// ---------------------------------------------------------------------------
__global__ __launch_bounds__(256) void prep_kernel(
    const float* __restrict__ x, const float* __restrict__ w,
    _Float16* __restrict__ xp_hi, _Float16* __restrict__ xp_lo,
    _Float16* __restrict__ wt_hi, _Float16* __restrict__ wt_lo)
{
    int b = blockIdx.x;
    int tid = threadIdx.x;
    if (b < 1024) {
        int t = b * 256 + tid;                 // oc*512 + ic
#pragma unroll
        for (int q = 0; q < 9; ++q) {
            float v = w[(size_t)t * 9 + q];
            _Float16 hi = (_Float16)v;
            _Float16 lo = (_Float16)(v - (float)hi);
            wt_hi[(size_t)q * 262144 + t] = hi;
            wt_lo[(size_t)q * 262144 + t] = lo;
        }
    } else if (b < 1152) {
        __shared__ float xs[64][65];
        int bb = b - 1024;
        int ic0 = (bb & 7) * 64;
        int pix0 = (bb >> 3) * 64;
#pragma unroll
        for (int r = 0; r < 16; ++r) {
            int i = r * 4 + (tid >> 6);
            int j = tid & 63;
            xs[i][j] = x[(size_t)(ic0 + i) * NPIX + pix0 + j];
        }
        __syncthreads();
#pragma unroll
        for (int rr = 0; rr < 16; ++rr) {
            int j = rr * 4 + (tid >> 6);
            int i = tid & 63;
            float v = xs[i][j];
            int p = pix0 + j;
            int row = ((p >> 5) + 1) * 34 + (p & 31) + 1;
            _Float16 hi = (_Float16)v;
            _Float16 lo = (_Float16)(v - (float)hi);
            xp_hi[(size_t)row * 512 + ic0 + i] = hi;
            xp_lo[(size_t)row * 512 + ic0 + i] = lo;
        }
    } else {
        int base = (b - 1152) * 256 + tid;
        for (int e = base; e < 132 * 512; e += 36 * 256) {
            int br = e >> 9;
            int ic = e & 511;
            int row;
            if (br < 34) row = br;
            else if (br < 68) row = 33 * 34 + (br - 34);
            else { int c2 = br - 68; row = (1 + (c2 >> 1)) * 34 + (c2 & 1) * 33; }
            xp_hi[(size_t)row * 512 + ic] = (_Float16)0.f;
            xp_lo[(size_t)row * 512 + ic] = (_Float16)0.f;
        }
    }
}

// ---------------------------------------------------------------------------
// conv_gemm: M=1024 px, N=512 oc, K=4608, split-K x2 (2304 each).
// Grid 512 = 2 blocks/CU so one block's compute covers the other's barrier
// drain. Block: 128 thr (2 waves), BM=32 (one image row), BN=64, BK=64;
// wave tile 32x32 (waves share A via LDS broadcast). fp16 3-pass split.
// LDS XOR-swizzle via pre-swizzled global source (global_load_lds is linear).
// Writes raw fp32 partials part[ks][pix][oc]; bias/relu deferred to head.
// ---------------------------------------------------------------------------
#define BUFSZ 24576   // A_hi 4K | A_lo 4K | B_hi 8K | B_lo 8K
__global__ __launch_bounds__(128) void conv_gemm_kernel(
    const _Float16* __restrict__ xp_hi, const _Float16* __restrict__ xp_lo,
    const _Float16* __restrict__ wt_hi, const _Float16* __restrict__ wt_lo,
    float* __restrict__ part)
{
    __shared__ __align__(16) char smem[2 * BUFSZ];   // 48 KB
    int bid = blockIdx.x;
    // XCD x: oc-panels {(x&3)*2, (x&3)*2+1}, K-split x>>2 -> B+A slice L2-fits
    int xcd = bid & 7, rest = bid >> 3;
    int nt = (xcd & 3) * 2 + (rest & 1);   // 0..7 oc tile
    int ks = xcd >> 2;                     // 0..1 K split
    int mt = rest >> 1;                    // 0..31 image row
    int oc0 = nt * 64;
    int kb0 = ks * 36;

    int tid = threadIdx.x;
    int wave = tid >> 6, lane = tid & 63;

    // staging: 8-row chunks of 128B rows; per-lane pre-swizzled source col
    int r8 = lane >> 3;                                   // row within chunk
    int khalf = ((((lane & 7) * 16) ^ (r8 << 4)) >> 1);   // source elem offset
    const _Float16* srcAh = xp_hi + (size_t)(mt * 34 + r8) * 512 + khalf;
    const _Float16* srcAl = xp_lo + (size_t)(mt * 34 + r8) * 512 + khalf;
    const _Float16* srcBh = wt_hi + (size_t)(oc0 + r8) * 512 + khalf;
    const _Float16* srcBl = wt_lo + (size_t)(oc0 + r8) * 512 + khalf;
    int cA0 = wave, cA1 = wave + 2;        // A chunks per wave (of 4)

#define STAGE(kb, bufb) do {                                                    \
        int q_ = (kb) >> 3, icc_ = (kb) & 7;                                    \
        int qy_ = (q_ * 11) >> 5; int qx_ = q_ - qy_ * 3;                       \
        size_t ao_ = (size_t)(qy_ * 34 + qx_) * 512 + icc_ * 64;                \
        size_t bo_ = (size_t)q_ * 262144 + icc_ * 64;                           \
        char* bb_ = smem + (bufb);                                              \
        GLOAD16(srcAh + ao_ + cA0 * 4096, bb_ + cA0 * 1024);                    \
        GLOAD16(srcAh + ao_ + cA1 * 4096, bb_ + cA1 * 1024);                    \
        GLOAD16(srcAl + ao_ + cA0 * 4096, bb_ + 4096 + cA0 * 1024);             \
        GLOAD16(srcAl + ao_ + cA1 * 4096, bb_ + 4096 + cA1 * 1024);             \
        GLOAD16(srcBh + bo_ + (wave) * 4096,     bb_ + 8192  + (wave) * 1024);  \
        GLOAD16(srcBh + bo_ + (wave + 2) * 4096, bb_ + 8192  + (wave + 2) * 1024); \
        GLOAD16(srcBh + bo_ + (wave + 4) * 4096, bb_ + 8192  + (wave + 4) * 1024); \
        GLOAD16(srcBh + bo_ + (wave + 6) * 4096, bb_ + 8192  + (wave + 6) * 1024); \
        GLOAD16(srcBl + bo_ + (wave) * 4096,     bb_ + 16384 + (wave) * 1024);  \
        GLOAD16(srcBl + bo_ + (wave + 2) * 4096, bb_ + 16384 + (wave + 2) * 1024); \
        GLOAD16(srcBl + bo_ + (wave + 4) * 4096, bb_ + 16384 + (wave + 4) * 1024); \
        GLOAD16(srcBl + bo_ + (wave + 6) * 4096, bb_ + 16384 + (wave + 6) * 1024); \
    } while (0)

    // compute-side addressing (wave wn owns oc cols wn*32..+31, all 32 px)
    int wn = wave;
    int ml = lane & 15, kq = lane >> 4;
    int swz = (ml & 7) << 4;
    int aoff = ml * 128 + ((kq * 16) ^ swz);
    int boff = (wn * 32 + ml) * 128 + ((kq * 16) ^ swz);

    f32x4 hh[2][2], co[2][2];
#pragma unroll
    for (int m = 0; m < 2; ++m)
#pragma unroll
        for (int n = 0; n < 2; ++n) { hh[m][n] = (f32x4)0.f; co[m][n] = (f32x4)0.f; }

#define MF(a, b, c) __builtin_amdgcn_mfma_f32_16x16x32_f16(a, b, c, 0, 0, 0)
#define COMPUTE(bufb) do {                                                      \
        const char* bb_ = smem + (bufb);                                        \
        _Pragma("unroll")                                                       \
        for (int s2 = 0; s2 < 2; ++s2) {                                        \
            int kx_ = s2 * 64;                                                  \
            half8 ah0 = *(const half8*)(bb_ + (aoff ^ kx_));                    \
            half8 ah1 = *(const half8*)(bb_ + 2048  + (aoff ^ kx_));            \
            half8 al0 = *(const half8*)(bb_ + 4096  + (aoff ^ kx_));            \
            half8 al1 = *(const half8*)(bb_ + 6144  + (aoff ^ kx_));            \
            half8 bh0 = *(const half8*)(bb_ + 8192  + (boff ^ kx_));            \
            half8 bh1 = *(const half8*)(bb_ + 10240 + (boff ^ kx_));            \
            half8 bl0 = *(const half8*)(bb_ + 16384 + (boff ^ kx_));            \
            half8 bl1 = *(const half8*)(bb_ + 18432 + (boff ^ kx_));            \
            hh[0][0] = MF(ah0, bh0, hh[0][0]);                                  \
            hh[0][1] = MF(ah0, bh1, hh[0][1]);                                  \
            hh[1][0] = MF(ah1, bh0, hh[1][0]);                                  \
            hh[1][1] = MF(ah1, bh1, hh[1][1]);                                  \
            co[0][0] = MF(ah0, bl0, co[0][0]); co[0][0] = MF(al0, bh0, co[0][0]); \
            co[0][1] = MF(ah0, bl1, co[0][1]); co[0][1] = MF(al0, bh1, co[0][1]); \
            co[1][0] = MF(ah1, bl0, co[1][0]); co[1][0] = MF(al1, bh0, co[1][0]); \
            co[1][1] = MF(ah1, bl1, co[1][1]); co[1][1] = MF(al1, bh1, co[1][1]); \
        }                                                                       \
    } while (0)

    STAGE(kb0, 0);
    __syncthreads();
    int buf = 0;
    for (int i = 0; i < 36; ++i) {
        if (i < 35) STAGE(kb0 + i + 1, (buf ^ 1) * BUFSZ);
        COMPUTE(buf * BUFSZ);
        __syncthreads();
        buf ^= 1;
    }

    // raw partial write; C layout col=lane&15, row=(lane>>4)*4+j (R3-verified)
    float* outp = part + (size_t)ks * 524288;
#pragma unroll
    for (int m = 0; m < 2; ++m)
#pragma unroll
        for (int n = 0; n < 2; ++n) {
            int oc = oc0 + wn * 32 + n * 16 + ml;
#pragma unroll
            for (int j = 0; j < 4; ++j) {
                int pixc = m * 16 + kq * 4 + j;
                outp[(size_t)(mt * 32 + pixc) * 512 + oc] = hh[m][n][j] + co[m][n][j];
            }
        }
#undef STAGE
#undef COMPUTE
#undef MF
}

// ---------------------------------------------------------------------------
// head: sum K-partials + conv bias + relu, then 1x1 heads (54 dots over 512),
// softmax pairs, anchor construct + deparameterize. One block per pixel.
// ---------------------------------------------------------------------------
__global__ __launch_bounds__(64) void head_kernel(
    const float* __restrict__ part, const float* __restrict__ b_win,
    const float* __restrict__ w_cls, const float* __restrict__ b_cls,
    const float* __restrict__ w_reg, const float* __restrict__ b_reg,
    const float* __restrict__ anchors_wh,
    float* __restrict__ boxes, float* __restrict__ probs)
{
    int p = blockIdx.x;
    int tid = threadIdx.x;

    __shared__ float fs[CIN];
    __shared__ float dots[54];

    const float4* p0 = (const float4*)(part + (size_t)p * 512);
    const float4* p1 = (const float4*)(part + 524288 + (size_t)p * 512);
    const float4* bw = (const float4*)b_win;
    float4* fs4 = (float4*)fs;
    for (int i = tid; i < CIN / 4; i += 64) {
        float4 a = p0[i], b = p1[i], c = bw[i];
        float4 r;
        r.x = fmaxf(a.x + b.x + c.x, 0.f);
        r.y = fmaxf(a.y + b.y + c.y, 0.f);
        r.z = fmaxf(a.z + b.z + c.z, 0.f);
        r.w = fmaxf(a.w + b.w + c.w, 0.f);
        fs4[i] = r;
    }
    __syncthreads();

    if (tid < 54) {
        const float* wr = (tid < 18) ? (w_cls + (size_t)tid * CIN)
                                     : (w_reg + (size_t)(tid - 18) * CIN);
        float bv = (tid < 18) ? b_cls[tid] : b_reg[tid - 18];
        const float4* w4 = (const float4*)wr;
        float s0 = 0.f, s1 = 0.f, s2 = 0.f, s3 = 0.f;
#pragma unroll 8
        for (int i = 0; i < CIN / 4; ++i) {
            float4 f = fs4[i];
            float4 wv = w4[i];
            s0 = fmaf(f.x, wv.x, s0);
            s1 = fmaf(f.y, wv.y, s1);
            s2 = fmaf(f.z, wv.z, s2);
            s3 = fmaf(f.w, wv.w, s3);
        }
        dots[tid] = ((s0 + s1) + (s2 + s3)) + bv;
    }
    __syncthreads();

    if (tid < NA) {
        int a = tid;
        float c0 = dots[2 * a], c1 = dots[2 * a + 1];
        float m = fmaxf(c0, c1);
        float e0 = expf(c0 - m), e1 = expf(c1 - m);
        float inv = 1.f / (e0 + e1);
        float p0s = e0 * inv, p1s = e1 * inv;

        int ih = p >> 5, iw = p & 31;        // ih pairs with box x (reference)
        float wa = anchors_wh[2 * a + 0];
        float ha = anchors_wh[2 * a + 1];
        float fih = (float)ih, fiw = (float)iw;
        float ax1 = (-(wa / 2.0f) + fih) / 32.0f;
        float ay1 = (-(ha / 2.0f) + fiw) / 32.0f;
        float ax2 = ((wa / 2.0f) + fih) / 32.0f;
        float ay2 = ((ha / 2.0f) + fiw) / 32.0f;
        float wab = ax2 - ax1;
        float hab = ay2 - ay1;
        float xa = (ax1 + ax2) * 0.5f;
        float ya = (ay1 + ay2) * 0.5f;

        float rg0 = dots[18 + 4 * a + 0];
        float rg1 = dots[18 + 4 * a + 1];
        float rg2 = dots[18 + 4 * a + 2];
        float rg3 = dots[18 + 4 * a + 3];
        float xc = rg0 * wab + xa;
        float yc = rg1 * hab + ya;
        float bw2 = expf(rg2) * wab;
        float bh2 = expf(rg3) * hab;

        int idx = p * NA + a;
        float4 bx;
        bx.x = xc - bw2 / 2.0f;
        bx.y = yc - bh2 / 2.0f;
        bx.z = xc + bw2 / 2.0f;
        bx.w = yc + bh2 / 2.0f;
        ((float4*)boxes)[idx] = bx;
        probs[idx * 2 + 0] = p0s;
        probs[idx * 2 + 1] = p1s;
    }
}

// ---------------------------------------------------------------------------
// nms: greedy top-5, register-resident. Each of 1024 threads owns 9 boxes +
// scores in VGPRs; argmax = reg scan + shfl + 16-entry LDS reduce; suppress
// is pure-reg IoU. Equivalent to reference stable-sorted scan NMS.
// ---------------------------------------------------------------------------
__global__ __launch_bounds__(1024) void nms_kernel(
    const float* __restrict__ boxes, const float* __restrict__ probs,
    float* __restrict__ out)
{
    __shared__ float redv[16];
    __shared__ int   redi[16];
    __shared__ int   keep[NOUT];
    __shared__ float bbox[4];

    int tid = threadIdx.x;
    float4 myb[9];
    float  mys[9];
#pragma unroll
    for (int j = 0; j < 9; ++j) {
        int i = j * 1024 + tid;
        myb[j] = ((const float4*)boxes)[i];
        mys[j] = probs[2 * i];
    }

    for (int k = 0; k < NOUT; ++k) {
        float bv = -1e30f;
        int   bi = NBOX;
#pragma unroll
        for (int j = 0; j < 9; ++j) {
            int idx = j * 1024 + tid;
            float v = mys[j];
            if (v > bv || (v == bv && idx < bi)) { bv = v; bi = idx; }
        }
#pragma unroll
        for (int off = 32; off > 0; off >>= 1) {
            float ov = __shfl_down(bv, off);
            int   oi = __shfl_down(bi, off);
            if (ov > bv || (ov == bv && oi < bi)) { bv = ov; bi = oi; }
        }
        if ((tid & 63) == 0) { redv[tid >> 6] = bv; redi[tid >> 6] = bi; }
        __syncthreads();
        if (tid == 0) {
            float fv = redv[0]; int fi = redi[0];
#pragma unroll
            for (int w = 1; w < 16; ++w)
                if (redv[w] > fv || (redv[w] == fv && redi[w] < fi)) { fv = redv[w]; fi = redi[w]; }
            keep[k] = fi;
            float4 pb = ((const float4*)boxes)[fi];
            bbox[0] = pb.x; bbox[1] = pb.y; bbox[2] = pb.z; bbox[3] = pb.w;
        }
        __syncthreads();
        float bx0 = bbox[0], bx1 = bbox[1], bx2 = bbox[2], bx3 = bbox[3];
        float aa = (bx2 - bx0) * (bx3 - bx1);
#pragma unroll
        for (int j = 0; j < 9; ++j) {
            float4 bb = myb[j];
            float ltx = fmaxf(bx0, bb.x);
            float lty = fmaxf(bx1, bb.y);
            float rbx = fminf(bx2, bb.z);
            float rby = fminf(bx3, bb.w);
            float iw2 = fmaxf(rbx - ltx, 0.f);
            float ih2 = fmaxf(rby - lty, 0.f);
            float inter = iw2 * ih2;
            float ab = (bb.z - bb.x) * (bb.w - bb.y);
            float iou = inter / (aa + ab - inter);
            if (iou > NMS_THR) mys[j] = -1e30f;   // pick itself: iou=1 -> gone
        }
        // no barrier needed: suppression is thread-local; shared state is
        // re-written only after the next iteration's post-redv barrier.
    }

    if (tid < NOUT) {
        int ki = keep[tid];
        out[tid * 2 + 0] = probs[(size_t)ki * 2 + 0];
        out[tid * 2 + 1] = probs[(size_t)ki * 2 + 1];
        out[2 * NOUT + tid * 4 + 0] = boxes[(size_t)ki * 4 + 0];
        out[2 * NOUT + tid * 4 + 1] = boxes[(size_t)ki * 4 + 1];
        out[2 * NOUT + tid * 4 + 2] = boxes[(size_t)ki * 4 + 2];
        out[2 * NOUT + tid * 4 + 3] = boxes[(size_t)ki * 4 + 3];
    }
}

// ---------------------------------------------------------------------------
extern "C" void kernel_launch(void* const* d_in, const int* in_sizes, int n_in,
                              void* d_out, int out_size, void* d_ws, size_t ws_size,
                              hipStream_t stream)
{
    const float* x          = (const float*)d_in[0];
    const float* w_win      = (const float*)d_in[1];
    const float* b_win      = (const float*)d_in[2];
    const float* w_cls      = (const float*)d_in[3];
    const float* b_cls      = (const float*)d_in[4];
    const float* w_reg      = (const float*)d_in[5];
    const float* b_reg      = (const float*)d_in[6];
    const float* anchors_wh = (const float*)d_in[7];

    char* wsb = (char*)d_ws;
    float*     part   = (float*)(wsb);                    // 4,194,304 B [2][1024][512]
    float*     boxes  = (float*)(wsb + 4194304);          //   147,456 B
    float*     probs  = (float*)(wsb + 4341760);          //    73,728 B
    _Float16*  xp_hi  = (_Float16*)(wsb + 4415488);       // 1,183,744 B
    _Float16*  xp_lo  = (_Float16*)(wsb + 5599232);       // 1,183,744 B
    _Float16*  wt_hi  = (_Float16*)(wsb + 6782976);       // 4,718,592 B
    _Float16*  wt_lo  = (_Float16*)(wsb + 11501568);      // 4,718,592 B (end 16.2 MB)

    prep_kernel<<<1188, 256, 0, stream>>>(x, w_win, xp_hi, xp_lo, wt_hi, wt_lo);
    conv_gemm_kernel<<<512, 128, 0, stream>>>(xp_hi, xp_lo, wt_hi, wt_lo, part);
    head_kernel<<<NPIX, 64, 0, stream>>>(part, b_win, w_cls, b_cls, w_reg, b_reg,
                                         anchors_wh, boxes, probs);
    nms_kernel<<<1, 1024, 0, stream>>>(boxes, probs, (float*)d_out);
}

// Round 8
// 140.006 us; speedup vs baseline: 5.7060x; 1.0351x over previous
//
#include <hip/hip_runtime.h>
#include <math.h>

// RPN forward: conv3x3 as MFMA implicit-GEMM (fp16 hi/lo 3-pass split, fp32-like
// accuracy, split-K x2 for 2 blocks/CU) -> fused reduce+bias+relu+1x1 heads
// (transposed-weight coalesced) -> register-resident greedy NMS top-5.

#define HH 32
#define WW 32
#define NPIX 1024
#define CIN 512
#define COUT 512
#define NA 9
#define NBOX (NPIX * NA)
#define NMS_THR 0.7f
#define NOUT 5

typedef _Float16 half8 __attribute__((ext_vector_type(8)));
typedef float f32x4 __attribute__((ext_vector_type(4)));

#define GLOAD16(src, dst) \
    __builtin_amdgcn_global_load_lds((const __attribute__((address_space(1))) void*)(src), \
                                     (__attribute__((address_space(3))) void*)(dst), 16, 0, 0)

// ---------------------------------------------------------------------------
// prep: fused preprocessing.
//  blocks 0..1023   : w OIHW -> wt[q][oc][ic] fp16 hi/lo
//  blocks 1024..1151: x -> zero-padded pixel-major fp16 hi/lo xp[34*34][512]
//  blocks 1152..1187: rewrite the 132 border pixel-rows (ws re-poisoned 0xAA)
//  blocks 1188..1195: head weights -> wt_head[ic][64] fp32 (cls||reg, pad 64)
//                     + bias_head[64]
// ---------------------------------------------------------------------------
__global__ __launch_bounds__(256) void prep_kernel(
    const float* __restrict__ x, const float* __restrict__ w,
    const float* __restrict__ w_cls, const float* __restrict__ b_cls,
    const float* __restrict__ w_reg, const float* __restrict__ b_reg,
    _Float16* __restrict__ xp_hi, _Float16* __restrict__ xp_lo,
    _Float16* __restrict__ wt_hi, _Float16* __restrict__ wt_lo,
    float* __restrict__ wt_head, float* __restrict__ bias_head)
{
    int b = blockIdx.x;
    int tid = threadIdx.x;
    if (b < 1024) {
        int t = b * 256 + tid;                 // oc*512 + ic
#pragma unroll
        for (int q = 0; q < 9; ++q) {
            float v = w[(size_t)t * 9 + q];
            _Float16 hi = (_Float16)v;
            _Float16 lo = (_Float16)(v - (float)hi);
            wt_hi[(size_t)q * 262144 + t] = hi;
            wt_lo[(size_t)q * 262144 + t] = lo;
        }
    } else if (b < 1152) {
        __shared__ float xs[64][65];
        int bb = b - 1024;
        int ic0 = (bb & 7) * 64;
        int pix0 = (bb >> 3) * 64;
#pragma unroll
        for (int r = 0; r < 16; ++r) {
            int i = r * 4 + (tid >> 6);
            int j = tid & 63;
            xs[i][j] = x[(size_t)(ic0 + i) * NPIX + pix0 + j];
        }
        __syncthreads();
#pragma unroll
        for (int rr = 0; rr < 16; ++rr) {
            int j = rr * 4 + (tid >> 6);
            int i = tid & 63;
            float v = xs[i][j];
            int p = pix0 + j;
            int row = ((p >> 5) + 1) * 34 + (p & 31) + 1;
            _Float16 hi = (_Float16)v;
            _Float16 lo = (_Float16)(v - (float)hi);
            xp_hi[(size_t)row * 512 + ic0 + i] = hi;
            xp_lo[(size_t)row * 512 + ic0 + i] = lo;
        }
    } else if (b < 1188) {
        int base = (b - 1152) * 256 + tid;
        for (int e = base; e < 132 * 512; e += 36 * 256) {
            int br = e >> 9;
            int ic = e & 511;
            int row;
            if (br < 34) row = br;
            else if (br < 68) row = 33 * 34 + (br - 34);
            else { int c2 = br - 68; row = (1 + (c2 >> 1)) * 34 + (c2 & 1) * 33; }
            xp_hi[(size_t)row * 512 + ic] = (_Float16)0.f;
            xp_lo[(size_t)row * 512 + ic] = (_Float16)0.f;
        }
    } else {
        // head-weight transpose: wt_head[ic*64+o], o = cls 0..17 | reg 18..53 | pad
        int t = (b - 1188) * 256 + tid;        // 0..2047
        int o = t & 63;
        int ic0 = (t >> 6) * 16;               // 0..496
#pragma unroll
        for (int k = 0; k < 16; ++k) {
            int ic = ic0 + k;
            float v = 0.f;
            if (o < 18)      v = w_cls[(size_t)o * CIN + ic];
            else if (o < 54) v = w_reg[(size_t)(o - 18) * CIN + ic];
            wt_head[(size_t)ic * 64 + o] = v;
        }
        if (t < 64) {
            float bv = 0.f;
            if (t < 18)      bv = b_cls[t];
            else if (t < 54) bv = b_reg[t - 18];
            bias_head[t] = bv;
        }
    }
}

// ---------------------------------------------------------------------------
// conv_gemm: M=1024 px, N=512 oc, K=4608, split-K x2 (2304 each).  [FROZEN R7]
// Grid 512 = 2 blocks/CU so one block's compute covers the other's barrier
// drain. Block: 128 thr (2 waves), BM=32 (one image row), BN=64, BK=64;
// wave tile 32x32. fp16 3-pass split. LDS XOR-swizzle via pre-swizzled source.
// Writes raw fp32 partials part[ks][pix][oc]; bias/relu deferred to head.
// ---------------------------------------------------------------------------
#define BUFSZ 24576   // A_hi 4K | A_lo 4K | B_hi 8K | B_lo 8K
__global__ __launch_bounds__(128) void conv_gemm_kernel(
    const _Float16* __restrict__ xp_hi, const _Float16* __restrict__ xp_lo,
    const _Float16* __restrict__ wt_hi, const _Float16* __restrict__ wt_lo,
    float* __restrict__ part)
{
    __shared__ __align__(16) char smem[2 * BUFSZ];   // 48 KB
    int bid = blockIdx.x;
    int xcd = bid & 7, rest = bid >> 3;
    int nt = (xcd & 3) * 2 + (rest & 1);   // 0..7 oc tile
    int ks = xcd >> 2;                     // 0..1 K split
    int mt = rest >> 1;                    // 0..31 image row
    int oc0 = nt * 64;
    int kb0 = ks * 36;

    int tid = threadIdx.x;
    int wave = tid >> 6, lane = tid & 63;

    int r8 = lane >> 3;
    int khalf = ((((lane & 7) * 16) ^ (r8 << 4)) >> 1);
    const _Float16* srcAh = xp_hi + (size_t)(mt * 34 + r8) * 512 + khalf;
    const _Float16* srcAl = xp_lo + (size_t)(mt * 34 + r8) * 512 + khalf;
    const _Float16* srcBh = wt_hi + (size_t)(oc0 + r8) * 512 + khalf;
    const _Float16* srcBl = wt_lo + (size_t)(oc0 + r8) * 512 + khalf;
    int cA0 = wave, cA1 = wave + 2;

#define STAGE(kb, bufb) do {                                                    \
        int q_ = (kb) >> 3, icc_ = (kb) & 7;                                    \
        int qy_ = (q_ * 11) >> 5; int qx_ = q_ - qy_ * 3;                       \
        size_t ao_ = (size_t)(qy_ * 34 + qx_) * 512 + icc_ * 64;                \
        size_t bo_ = (size_t)q_ * 262144 + icc_ * 64;                           \
        char* bb_ = smem + (bufb);                                              \
        GLOAD16(srcAh + ao_ + cA0 * 4096, bb_ + cA0 * 1024);                    \
        GLOAD16(srcAh + ao_ + cA1 * 4096, bb_ + cA1 * 1024);                    \
        GLOAD16(srcAl + ao_ + cA0 * 4096, bb_ + 4096 + cA0 * 1024);             \
        GLOAD16(srcAl + ao_ + cA1 * 4096, bb_ + 4096 + cA1 * 1024);             \
        GLOAD16(srcBh + bo_ + (wave) * 4096,     bb_ + 8192  + (wave) * 1024);  \
        GLOAD16(srcBh + bo_ + (wave + 2) * 4096, bb_ + 8192  + (wave + 2) * 1024); \
        GLOAD16(srcBh + bo_ + (wave + 4) * 4096, bb_ + 8192  + (wave + 4) * 1024); \
        GLOAD16(srcBh + bo_ + (wave + 6) * 4096, bb_ + 8192  + (wave + 6) * 1024); \
        GLOAD16(srcBl + bo_ + (wave) * 4096,     bb_ + 16384 + (wave) * 1024);  \
        GLOAD16(srcBl + bo_ + (wave + 2) * 4096, bb_ + 16384 + (wave + 2) * 1024); \
        GLOAD16(srcBl + bo_ + (wave + 4) * 4096, bb_ + 16384 + (wave + 4) * 1024); \
        GLOAD16(srcBl + bo_ + (wave + 6) * 4096, bb_ + 16384 + (wave + 6) * 1024); \
    } while (0)

    int wn = wave;
    int ml = lane & 15, kq = lane >> 4;
    int swz = (ml & 7) << 4;
    int aoff = ml * 128 + ((kq * 16) ^ swz);
    int boff = (wn * 32 + ml) * 128 + ((kq * 16) ^ swz);

    f32x4 hh[2][2], co[2][2];
#pragma unroll
    for (int m = 0; m < 2; ++m)
#pragma unroll
        for (int n = 0; n < 2; ++n) { hh[m][n] = (f32x4)0.f; co[m][n] = (f32x4)0.f; }

#define MF(a, b, c) __builtin_amdgcn_mfma_f32_16x16x32_f16(a, b, c, 0, 0, 0)
#define COMPUTE(bufb) do {                                                      \
        const char* bb_ = smem + (bufb);                                        \
        _Pragma("unroll")                                                       \
        for (int s2 = 0; s2 < 2; ++s2) {                                        \
            int kx_ = s2 * 64;                                                  \
            half8 ah0 = *(const half8*)(bb_ + (aoff ^ kx_));                    \
            half8 ah1 = *(const half8*)(bb_ + 2048  + (aoff ^ kx_));            \
            half8 al0 = *(const half8*)(bb_ + 4096  + (aoff ^ kx_));            \
            half8 al1 = *(const half8*)(bb_ + 6144  + (aoff ^ kx_));            \
            half8 bh0 = *(const half8*)(bb_ + 8192  + (boff ^ kx_));            \
            half8 bh1 = *(const half8*)(bb_ + 10240 + (boff ^ kx_));            \
            half8 bl0 = *(const half8*)(bb_ + 16384 + (boff ^ kx_));            \
            half8 bl1 = *(const half8*)(bb_ + 18432 + (boff ^ kx_));            \
            hh[0][0] = MF(ah0, bh0, hh[0][0]);                                  \
            hh[0][1] = MF(ah0, bh1, hh[0][1]);                                  \
            hh[1][0] = MF(ah1, bh0, hh[1][0]);                                  \
            hh[1][1] = MF(ah1, bh1, hh[1][1]);                                  \
            co[0][0] = MF(ah0, bl0, co[0][0]); co[0][0] = MF(al0, bh0, co[0][0]); \
            co[0][1] = MF(ah0, bl1, co[0][1]); co[0][1] = MF(al0, bh1, co[0][1]); \
            co[1][0] = MF(ah1, bl0, co[1][0]); co[1][0] = MF(al1, bh0, co[1][0]); \
            co[1][1] = MF(ah1, bl1, co[1][1]); co[1][1] = MF(al1, bh1, co[1][1]); \
        }                                                                       \
    } while (0)

    STAGE(kb0, 0);
    __syncthreads();
    int buf = 0;
    for (int i = 0; i < 36; ++i) {
        if (i < 35) STAGE(kb0 + i + 1, (buf ^ 1) * BUFSZ);
        COMPUTE(buf * BUFSZ);
        __syncthreads();
        buf ^= 1;
    }

    float* outp = part + (size_t)ks * 524288;
#pragma unroll
    for (int m = 0; m < 2; ++m)
#pragma unroll
        for (int n = 0; n < 2; ++n) {
            int oc = oc0 + wn * 32 + n * 16 + ml;
#pragma unroll
            for (int j = 0; j < 4; ++j) {
                int pixc = m * 16 + kq * 4 + j;
                outp[(size_t)(mt * 32 + pixc) * 512 + oc] = hh[m][n][j] + co[m][n][j];
            }
        }
#undef STAGE
#undef COMPUTE
#undef MF
}

// ---------------------------------------------------------------------------
// head v2: one wave per pixel. Stage relu(part0+part1+b_win) to LDS (float4),
// then lane o accumulates dot over ic with COALESCED wt_head[ic][o] reads
// (256B/wave/iter) + LDS broadcast, 4-way split accumulator chain.
// Softmax pairs + anchor deparameterize epilogue (lanes 0..8).
// ---------------------------------------------------------------------------
__global__ __launch_bounds__(64) void head_kernel(
    const float* __restrict__ part, const float* __restrict__ b_win,
    const float* __restrict__ wt_head, const float* __restrict__ bias_head,
    const float* __restrict__ anchors_wh,
    float* __restrict__ boxes, float* __restrict__ probs)
{
    int p = blockIdx.x;
    int lane = threadIdx.x;   // 0..63

    __shared__ float fs[CIN];
    __shared__ float dots[64];

    const float4* p0 = (const float4*)(part + (size_t)p * 512);
    const float4* p1 = (const float4*)(part + 524288 + (size_t)p * 512);
    const float4* bw = (const float4*)b_win;
    float4* fs4 = (float4*)fs;
#pragma unroll
    for (int i = 0; i < 2; ++i) {
        int j = i * 64 + lane;            // 0..127 float4 index
        float4 a = p0[j], b = p1[j], c = bw[j];
        float4 r;
        r.x = fmaxf(a.x + b.x + c.x, 0.f);
        r.y = fmaxf(a.y + b.y + c.y, 0.f);
        r.z = fmaxf(a.z + b.z + c.z, 0.f);
        r.w = fmaxf(a.w + b.w + c.w, 0.f);
        fs4[j] = r;
    }
    __syncthreads();

    {
        const float* wcol = wt_head + lane;
        float a0 = 0.f, a1 = 0.f, a2 = 0.f, a3 = 0.f;
#pragma unroll 8
        for (int ic = 0; ic < CIN; ic += 4) {
            a0 = fmaf(fs[ic + 0], wcol[(ic + 0) * 64], a0);
            a1 = fmaf(fs[ic + 1], wcol[(ic + 1) * 64], a1);
            a2 = fmaf(fs[ic + 2], wcol[(ic + 2) * 64], a2);
            a3 = fmaf(fs[ic + 3], wcol[(ic + 3) * 64], a3);
        }
        dots[lane] = ((a0 + a1) + (a2 + a3)) + bias_head[lane];
    }
    __syncthreads();

    if (lane < NA) {
        int a = lane;
        float c0 = dots[2 * a], c1 = dots[2 * a + 1];
        float m = fmaxf(c0, c1);
        float e0 = expf(c0 - m), e1 = expf(c1 - m);
        float inv = 1.f / (e0 + e1);
        float p0s = e0 * inv, p1s = e1 * inv;

        int ih = p >> 5, iw = p & 31;        // ih pairs with box x (reference)
        float wa = anchors_wh[2 * a + 0];
        float ha = anchors_wh[2 * a + 1];
        float fih = (float)ih, fiw = (float)iw;
        float ax1 = (-(wa / 2.0f) + fih) / 32.0f;
        float ay1 = (-(ha / 2.0f) + fiw) / 32.0f;
        float ax2 = ((wa / 2.0f) + fih) / 32.0f;
        float ay2 = ((ha / 2.0f) + fiw) / 32.0f;
        float wab = ax2 - ax1;
        float hab = ay2 - ay1;
        float xa = (ax1 + ax2) * 0.5f;
        float ya = (ay1 + ay2) * 0.5f;

        float rg0 = dots[18 + 4 * a + 0];
        float rg1 = dots[18 + 4 * a + 1];
        float rg2 = dots[18 + 4 * a + 2];
        float rg3 = dots[18 + 4 * a + 3];
        float xc = rg0 * wab + xa;
        float yc = rg1 * hab + ya;
        float bw2 = expf(rg2) * wab;
        float bh2 = expf(rg3) * hab;

        int idx = p * NA + a;
        float4 bx;
        bx.x = xc - bw2 / 2.0f;
        bx.y = yc - bh2 / 2.0f;
        bx.z = xc + bw2 / 2.0f;
        bx.w = yc + bh2 / 2.0f;
        ((float4*)boxes)[idx] = bx;
        probs[idx * 2 + 0] = p0s;
        probs[idx * 2 + 1] = p1s;
    }
}

// ---------------------------------------------------------------------------
// nms: greedy top-5, register-resident.  [FROZEN R7]
// ---------------------------------------------------------------------------
__global__ __launch_bounds__(1024) void nms_kernel(
    const float* __restrict__ boxes, const float* __restrict__ probs,
    float* __restrict__ out)
{
    __shared__ float redv[16];
    __shared__ int   redi[16];
    __shared__ int   keep[NOUT];
    __shared__ float bbox[4];

    int tid = threadIdx.x;
    float4 myb[9];
    float  mys[9];
#pragma unroll
    for (int j = 0; j < 9; ++j) {
        int i = j * 1024 + tid;
        myb[j] = ((const float4*)boxes)[i];
        mys[j] = probs[2 * i];
    }

    for (int k = 0; k < NOUT; ++k) {
        float bv = -1e30f;
        int   bi = NBOX;
#pragma unroll
        for (int j = 0; j < 9; ++j) {
            int idx = j * 1024 + tid;
            float v = mys[j];
            if (v > bv || (v == bv && idx < bi)) { bv = v; bi = idx; }
        }
#pragma unroll
        for (int off = 32; off > 0; off >>= 1) {
            float ov = __shfl_down(bv, off);
            int   oi = __shfl_down(bi, off);
            if (ov > bv || (ov == bv && oi < bi)) { bv = ov; bi = oi; }
        }
        if ((tid & 63) == 0) { redv[tid >> 6] = bv; redi[tid >> 6] = bi; }
        __syncthreads();
        if (tid == 0) {
            float fv = redv[0]; int fi = redi[0];
#pragma unroll
            for (int w = 1; w < 16; ++w)
                if (redv[w] > fv || (redv[w] == fv && redi[w] < fi)) { fv = redv[w]; fi = redi[w]; }
            keep[k] = fi;
            float4 pb = ((const float4*)boxes)[fi];
            bbox[0] = pb.x; bbox[1] = pb.y; bbox[2] = pb.z; bbox[3] = pb.w;
        }
        __syncthreads();
        float bx0 = bbox[0], bx1 = bbox[1], bx2 = bbox[2], bx3 = bbox[3];
        float aa = (bx2 - bx0) * (bx3 - bx1);
#pragma unroll
        for (int j = 0; j < 9; ++j) {
            float4 bb = myb[j];
            float ltx = fmaxf(bx0, bb.x);
            float lty = fmaxf(bx1, bb.y);
            float rbx = fminf(bx2, bb.z);
            float rby = fminf(bx3, bb.w);
            float iw2 = fmaxf(rbx - ltx, 0.f);
            float ih2 = fmaxf(rby - lty, 0.f);
            float inter = iw2 * ih2;
            float ab = (bb.z - bb.x) * (bb.w - bb.y);
            float iou = inter / (aa + ab - inter);
            if (iou > NMS_THR) mys[j] = -1e30f;
        }
    }

    if (tid < NOUT) {
        int ki = keep[tid];
        out[tid * 2 + 0] = probs[(size_t)ki * 2 + 0];
        out[tid * 2 + 1] = probs[(size_t)ki * 2 + 1];
        out[2 * NOUT + tid * 4 + 0] = boxes[(size_t)ki * 4 + 0];
        out[2 * NOUT + tid * 4 + 1] = boxes[(size_t)ki * 4 + 1];
        out[2 * NOUT + tid * 4 + 2] = boxes[(size_t)ki * 4 + 2];
        out[2 * NOUT + tid * 4 + 3] = boxes[(size_t)ki * 4 + 3];
    }
}

// ---------------------------------------------------------------------------
extern "C" void kernel_launch(void* const* d_in, const int* in_sizes, int n_in,
                              void* d_out, int out_size, void* d_ws, size_t ws_size,
                              hipStream_t stream)
{
    const float* x          = (const float*)d_in[0];
    const float* w_win      = (const float*)d_in[1];
    const float* b_win      = (const float*)d_in[2];
    const float* w_cls      = (const float*)d_in[3];
    const float* b_cls      = (const float*)d_in[4];
    const float* w_reg      = (const float*)d_in[5];
    const float* b_reg      = (const float*)d_in[6];
    const float* anchors_wh = (const float*)d_in[7];

    char* wsb = (char*)d_ws;
    float*     part      = (float*)(wsb);                 // 4,194,304 B [2][1024][512]
    float*     boxes     = (float*)(wsb + 4194304);       //   147,456 B
    float*     probs     = (float*)(wsb + 4341760);       //    73,728 B
    _Float16*  xp_hi     = (_Float16*)(wsb + 4415488);    // 1,183,744 B
    _Float16*  xp_lo     = (_Float16*)(wsb + 5599232);    // 1,183,744 B
    _Float16*  wt_hi     = (_Float16*)(wsb + 6782976);    // 4,718,592 B
    _Float16*  wt_lo     = (_Float16*)(wsb + 11501568);   // 4,718,592 B
    float*     wt_head   = (float*)(wsb + 16220160);      //   131,072 B [512][64]
    float*     bias_head = (float*)(wsb + 16351232);      //       256 B (end ~16.35 MB)

    prep_kernel<<<1196, 256, 0, stream>>>(x, w_win, w_cls, b_cls, w_reg, b_reg,
                                          xp_hi, xp_lo, wt_hi, wt_lo,
                                          wt_head, bias_head);
    conv_gemm_kernel<<<512, 128, 0, stream>>>(xp_hi, xp_lo, wt_hi, wt_lo, part);
    head_kernel<<<NPIX, 64, 0, stream>>>(part, b_win, wt_head, bias_head,
                                         anchors_wh, boxes, probs);
    nms_kernel<<<1, 1024, 0, stream>>>(boxes, probs, (float*)d_out);
}

// Round 10
// 133.441 us; speedup vs baseline: 5.9868x; 1.0492x over previous
//
#include <hip/hip_runtime.h>
#include <math.h>

// RPN forward: conv3x3 as MFMA implicit-GEMM v3 (fp16 hi/lo 3-pass split,
// 64x64 wave tiles, A-halo staged once, split-K x8) -> fused reduce+bias+relu
// +1x1 heads (transposed weights) -> register-resident greedy NMS top-5.

#define HH 32
#define WW 32
#define NPIX 1024
#define CIN 512
#define COUT 512
#define NA 9
#define NBOX (NPIX * NA)
#define NMS_THR 0.7f
#define NOUT 5

typedef _Float16 half8 __attribute__((ext_vector_type(8)));
typedef float f32x4 __attribute__((ext_vector_type(4)));

#define GLOAD16(src, dst) \
    __builtin_amdgcn_global_load_lds((const __attribute__((address_space(1))) void*)(src), \
                                     (__attribute__((address_space(3))) void*)(dst), 16, 0, 0)

// ---------------------------------------------------------------------------
// prep: fused preprocessing.  [FROZEN R8]
//  blocks 0..1023   : w OIHW -> wt[q][oc][ic] fp16 hi/lo
//  blocks 1024..1151: x -> zero-padded pixel-major fp16 hi/lo xp[34*34][512]
//  blocks 1152..1187: rewrite the 132 border pixel-rows (ws re-poisoned 0xAA)
//  blocks 1188..1195: head weights -> wt_head[ic][64] fp32 + bias_head[64]
// ---------------------------------------------------------------------------
__global__ __launch_bounds__(256) void prep_kernel(
    const float* __restrict__ x, const float* __restrict__ w,
    const float* __restrict__ w_cls, const float* __restrict__ b_cls,
    const float* __restrict__ w_reg, const float* __restrict__ b_reg,
    _Float16* __restrict__ xp_hi, _Float16* __restrict__ xp_lo,
    _Float16* __restrict__ wt_hi, _Float16* __restrict__ wt_lo,
    float* __restrict__ wt_head, float* __restrict__ bias_head)
{
    int b = blockIdx.x;
    int tid = threadIdx.x;
    if (b < 1024) {
        int t = b * 256 + tid;                 // oc*512 + ic
#pragma unroll
        for (int q = 0; q < 9; ++q) {
            float v = w[(size_t)t * 9 + q];
            _Float16 hi = (_Float16)v;
            _Float16 lo = (_Float16)(v - (float)hi);
            wt_hi[(size_t)q * 262144 + t] = hi;
            wt_lo[(size_t)q * 262144 + t] = lo;
        }
    } else if (b < 1152) {
        __shared__ float xs[64][65];
        int bb = b - 1024;
        int ic0 = (bb & 7) * 64;
        int pix0 = (bb >> 3) * 64;
#pragma unroll
        for (int r = 0; r < 16; ++r) {
            int i = r * 4 + (tid >> 6);
            int j = tid & 63;
            xs[i][j] = x[(size_t)(ic0 + i) * NPIX + pix0 + j];
        }
        __syncthreads();
#pragma unroll
        for (int rr = 0; rr < 16; ++rr) {
            int j = rr * 4 + (tid >> 6);
            int i = tid & 63;
            float v = xs[i][j];
            int p = pix0 + j;
            int row = ((p >> 5) + 1) * 34 + (p & 31) + 1;
            _Float16 hi = (_Float16)v;
            _Float16 lo = (_Float16)(v - (float)hi);
            xp_hi[(size_t)row * 512 + ic0 + i] = hi;
            xp_lo[(size_t)row * 512 + ic0 + i] = lo;
        }
    } else if (b < 1188) {
        int base = (b - 1152) * 256 + tid;
        for (int e = base; e < 132 * 512; e += 36 * 256) {
            int br = e >> 9;
            int ic = e & 511;
            int row;
            if (br < 34) row = br;
            else if (br < 68) row = 33 * 34 + (br - 34);
            else { int c2 = br - 68; row = (1 + (c2 >> 1)) * 34 + (c2 & 1) * 33; }
            xp_hi[(size_t)row * 512 + ic] = (_Float16)0.f;
            xp_lo[(size_t)row * 512 + ic] = (_Float16)0.f;
        }
    } else {
        int t = (b - 1188) * 256 + tid;        // 0..2047
        int o = t & 63;
        int ic0 = (t >> 6) * 16;
#pragma unroll
        for (int k = 0; k < 16; ++k) {
            int ic = ic0 + k;
            float v = 0.f;
            if (o < 18)      v = w_cls[(size_t)o * CIN + ic];
            else if (o < 54) v = w_reg[(size_t)(o - 18) * CIN + ic];
            wt_head[(size_t)ic * 64 + o] = v;
        }
        if (t < 64) {
            float bv = 0.f;
            if (t < 18)      bv = b_cls[t];
            else if (t < 54) bv = b_reg[t - 18];
            bias_head[t] = bv;
        }
    }
}

// ---------------------------------------------------------------------------
// conv_gemm v3: block tile 128px x 128oc, 4 waves (2x2) of 64x64 wave tiles
// built from verified 16x16x32 f16 frags. split-K x8: each block owns ONE
// 64-ic chunk x all 9 taps -> A-halo (6 xp-rows x 40px x 64ic, hi+lo, 60KB)
// staged ONCE; B (128oc x 64ic per tap, 32KB) double-buffered per q-step.
// 9 fat steps; LDS 124KB; grid 256 = 1 block/CU. fp16 3-pass split (hh + co).
// XCD map: bid = mtb*32 + nt2*8 + ks -> same (nt2,ks) blocks share an XCD.
// Writes raw fp32 partials part[ks][pix][oc].
// ---------------------------------------------------------------------------
#define A_LO 30720            // A_lo base (A_hi at 0); per half 6*40*128 B
#define B0_B 61440            // B buf0 (hi 16K | lo 16K)
#define B1_B 94208            // B buf1
#define BXOR (B0_B ^ B1_B)

__global__ __launch_bounds__(256) void conv_gemm_kernel(
    const _Float16* __restrict__ xp_hi, const _Float16* __restrict__ xp_lo,
    const _Float16* __restrict__ wt_hi, const _Float16* __restrict__ wt_lo,
    float* __restrict__ part)
{
    __shared__ __align__(16) char smem[126976];   // 124 KB

    int bid = blockIdx.x;
    int c   = bid & 31;
    int mtb = bid >> 5;          // 0..7  px tile (128 px = 4 image rows)
    int nt2 = c >> 3;            // 0..3  oc tile (128 oc)
    int ks  = c & 7;             // 0..7  ic chunk (64 ic)
    int oc0 = nt2 * 128;
    int icc = ks * 64;
    int r0x = mtb * 4;           // xp row base (needs xp rows r0x..r0x+5)

    int tid = threadIdx.x;
    int wave = tid >> 6, lane = tid & 63;
    int l3 = lane >> 3;
    int khalf = ((((lane & 7) * 16) ^ (l3 << 4)) >> 1);   // pre-swizzled src elem
    const _Float16* sAh = xp_hi + (size_t)l3 * 512 + khalf;
    const _Float16* sAl = xp_lo + (size_t)l3 * 512 + khalf;
    const _Float16* sBh = wt_hi + (size_t)l3 * 512 + khalf;
    const _Float16* sBl = wt_lo + (size_t)l3 * 512 + khalf;

    // ---- prologue: stage A halo (once) + B(q=0) into buf0 ----
    for (int g = wave; g < 30; g += 4) {
        int row = g / 5, pg = g - row * 5;                // 6 rows x 5 px-groups
        size_t so = ((size_t)(r0x + row) * 34 + pg * 8) * 512 + icc;
        int dd = (row * 40 + pg * 8) * 128;
        GLOAD16(sAh + so, smem + dd);
        GLOAD16(sAl + so, smem + A_LO + dd);
    }
#define STAGEB(q_, bbase) do {                                                 \
        size_t bo_ = (size_t)(q_) * 262144 + (size_t)oc0 * 512 + icc;          \
        for (int og = wave; og < 16; og += 4) {                                \
            size_t so_ = bo_ + (size_t)og * 8 * 512;                           \
            GLOAD16(sBh + so_, smem + (bbase) + og * 1024);                    \
            GLOAD16(sBl + so_, smem + (bbase) + 16384 + og * 1024);            \
        } } while (0)
    STAGEB(0, B0_B);
    __syncthreads();

    int wm = wave >> 1, wn = wave & 1;
    int ml = lane & 15, kq = lane >> 4;

    f32x4 hh[4][4], co[4][4];
#pragma unroll
    for (int m = 0; m < 4; ++m)
#pragma unroll
        for (int n = 0; n < 4; ++n) { hh[m][n] = (f32x4)0.f; co[m][n] = (f32x4)0.f; }

#define MF(a, b, cc) __builtin_amdgcn_mfma_f32_16x16x32_f16(a, b, cc, 0, 0, 0)

    int bb = B0_B;
#pragma unroll 1
    for (int q = 0; q < 9; ++q) {
        int qy = (q * 11) >> 5;
        int qx = q - qy * 3;
        if (q < 8) STAGEB(q + 1, bb ^ BXOR);

        int pswz = ((ml + qx) & 7) << 4;
        int bswz = (ml & 7) << 4;
#pragma unroll
        for (int k2 = 0; k2 < 2; ++k2) {
            int kb = k2 * 64 + kq * 16;
            half8 ah[4], al[4];
#pragma unroll
            for (int m = 0; m < 4; ++m) {
                int row = qy + wm * 2 + (m >> 1);
                int px  = (m & 1) * 16 + ml + qx;
                int ao  = (row * 40 + px) * 128 + (kb ^ pswz);
                ah[m] = *(const half8*)(smem + ao);
                al[m] = *(const half8*)(smem + A_LO + ao);
            }
#pragma unroll
            for (int n = 0; n < 4; ++n) {
                int bo = bb + (wn * 64 + n * 16 + ml) * 128 + (kb ^ bswz);
                half8 bh = *(const half8*)(smem + bo);
                half8 bl = *(const half8*)(smem + 16384 + bo);
#pragma unroll
                for (int m = 0; m < 4; ++m) {
                    hh[m][n] = MF(ah[m], bh, hh[m][n]);
                    co[m][n] = MF(ah[m], bl, co[m][n]);
                    co[m][n] = MF(al[m], bh, co[m][n]);
                }
            }
        }
        __syncthreads();
        bb ^= BXOR;
    }

    // epilogue: C layout col=lane&15 -> oc, row=(lane>>4)*4+j -> px (R3-verified)
    float* outp = part + (size_t)ks * 524288;
    int pxb = mtb * 128 + wm * 64;
#pragma unroll
    for (int m = 0; m < 4; ++m)
#pragma unroll
        for (int n = 0; n < 4; ++n) {
            int oc = oc0 + wn * 64 + n * 16 + ml;
#pragma unroll
            for (int j = 0; j < 4; ++j) {
                int px = pxb + m * 16 + kq * 4 + j;
                outp[(size_t)px * 512 + oc] = hh[m][n][j] + co[m][n][j];
            }
        }
#undef STAGEB
#undef MF
}

// ---------------------------------------------------------------------------
// head: sum 8 K-partials + conv bias + relu, then coalesced 1x1 heads
// (wt_head[ic][64]), softmax pairs + anchor deparameterize. 1 wave/pixel.
// ---------------------------------------------------------------------------
__global__ __launch_bounds__(64) void head_kernel(
    const float* __restrict__ part, const float* __restrict__ b_win,
    const float* __restrict__ wt_head, const float* __restrict__ bias_head,
    const float* __restrict__ anchors_wh,
    float* __restrict__ boxes, float* __restrict__ probs)
{
    int p = blockIdx.x;
    int lane = threadIdx.x;   // 0..63

    __shared__ float fs[CIN];
    __shared__ float dots[64];

    const float4* bw = (const float4*)b_win;
    float4* fs4 = (float4*)fs;
#pragma unroll
    for (int i = 0; i < 2; ++i) {
        int j = i * 64 + lane;            // 0..127 float4 index
        float4 r = bw[j];
#pragma unroll
        for (int s = 0; s < 8; ++s) {
            float4 a = ((const float4*)(part + (size_t)s * 524288 + (size_t)p * 512))[j];
            r.x += a.x; r.y += a.y; r.z += a.z; r.w += a.w;
        }
        r.x = fmaxf(r.x, 0.f);
        r.y = fmaxf(r.y, 0.f);
        r.z = fmaxf(r.z, 0.f);
        r.w = fmaxf(r.w, 0.f);
        fs4[j] = r;
    }
    __syncthreads();

    {
        const float* wcol = wt_head + lane;
        float a0 = 0.f, a1 = 0.f, a2 = 0.f, a3 = 0.f;
#pragma unroll 8
        for (int ic = 0; ic < CIN; ic += 4) {
            a0 = fmaf(fs[ic + 0], wcol[(ic + 0) * 64], a0);
            a1 = fmaf(fs[ic + 1], wcol[(ic + 1) * 64], a1);
            a2 = fmaf(fs[ic + 2], wcol[(ic + 2) * 64], a2);
            a3 = fmaf(fs[ic + 3], wcol[(ic + 3) * 64], a3);
        }
        dots[lane] = ((a0 + a1) + (a2 + a3)) + bias_head[lane];
    }
    __syncthreads();

    if (lane < NA) {
        int a = lane;
        float c0 = dots[2 * a], c1 = dots[2 * a + 1];
        float m = fmaxf(c0, c1);
        float e0 = expf(c0 - m), e1 = expf(c1 - m);
        float inv = 1.f / (e0 + e1);
        float p0s = e0 * inv, p1s = e1 * inv;

        int ih = p >> 5, iw = p & 31;        // ih pairs with box x (reference)
        float wa = anchors_wh[2 * a + 0];
        float ha = anchors_wh[2 * a + 1];
        float fih = (float)ih, fiw = (float)iw;
        float ax1 = (-(wa / 2.0f) + fih) / 32.0f;
        float ay1 = (-(ha / 2.0f) + fiw) / 32.0f;
        float ax2 = ((wa / 2.0f) + fih) / 32.0f;
        float ay2 = ((ha / 2.0f) + fiw) / 32.0f;
        float wab = ax2 - ax1;
        float hab = ay2 - ay1;
        float xa = (ax1 + ax2) * 0.5f;
        float ya = (ay1 + ay2) * 0.5f;

        float rg0 = dots[18 + 4 * a + 0];
        float rg1 = dots[18 + 4 * a + 1];
        float rg2 = dots[18 + 4 * a + 2];
        float rg3 = dots[18 + 4 * a + 3];
        float xc = rg0 * wab + xa;
        float yc = rg1 * hab + ya;
        float bw2 = expf(rg2) * wab;
        float bh2 = expf(rg3) * hab;

        int idx = p * NA + a;
        float4 bx;
        bx.x = xc - bw2 / 2.0f;
        bx.y = yc - bh2 / 2.0f;
        bx.z = xc + bw2 / 2.0f;
        bx.w = yc + bh2 / 2.0f;
        ((float4*)boxes)[idx] = bx;
        probs[idx * 2 + 0] = p0s;
        probs[idx * 2 + 1] = p1s;
    }
}

// ---------------------------------------------------------------------------
// nms: greedy top-5, register-resident.  [FROZEN R8]
// ---------------------------------------------------------------------------
__global__ __launch_bounds__(1024) void nms_kernel(
    const float* __restrict__ boxes, const float* __restrict__ probs,
    float* __restrict__ out)
{
    __shared__ float redv[16];
    __shared__ int   redi[16];
    __shared__ int   keep[NOUT];
    __shared__ float bbox[4];

    int tid = threadIdx.x;
    float4 myb[9];
    float  mys[9];
#pragma unroll
    for (int j = 0; j < 9; ++j) {
        int i = j * 1024 + tid;
        myb[j] = ((const float4*)boxes)[i];
        mys[j] = probs[2 * i];
    }

    for (int k = 0; k < NOUT; ++k) {
        float bv = -1e30f;
        int   bi = NBOX;
#pragma unroll
        for (int j = 0; j < 9; ++j) {
            int idx = j * 1024 + tid;
            float v = mys[j];
            if (v > bv || (v == bv && idx < bi)) { bv = v; bi = idx; }
        }
#pragma unroll
        for (int off = 32; off > 0; off >>= 1) {
            float ov = __shfl_down(bv, off);
            int   oi = __shfl_down(bi, off);
            if (ov > bv || (ov == bv && oi < bi)) { bv = ov; bi = oi; }
        }
        if ((tid & 63) == 0) { redv[tid >> 6] = bv; redi[tid >> 6] = bi; }
        __syncthreads();
        if (tid == 0) {
            float fv = redv[0]; int fi = redi[0];
#pragma unroll
            for (int w = 1; w < 16; ++w)
                if (redv[w] > fv || (redv[w] == fv && redi[w] < fi)) { fv = redv[w]; fi = redi[w]; }
            keep[k] = fi;
            float4 pb = ((const float4*)boxes)[fi];
            bbox[0] = pb.x; bbox[1] = pb.y; bbox[2] = pb.z; bbox[3] = pb.w;
        }
        __syncthreads();
        float bx0 = bbox[0], bx1 = bbox[1], bx2 = bbox[2], bx3 = bbox[3];
        float aa = (bx2 - bx0) * (bx3 - bx1);
#pragma unroll
        for (int j = 0; j < 9; ++j) {
            float4 bbx = myb[j];
            float ltx = fmaxf(bx0, bbx.x);
            float lty = fmaxf(bx1, bbx.y);
            float rbx = fminf(bx2, bbx.z);
            float rby = fminf(bx3, bbx.w);
            float iw2 = fmaxf(rbx - ltx, 0.f);
            float ih2 = fmaxf(rby - lty, 0.f);
            float inter = iw2 * ih2;
            float ab = (bbx.z - bbx.x) * (bbx.w - bbx.y);
            float iou = inter / (aa + ab - inter);
            if (iou > NMS_THR) mys[j] = -1e30f;
        }
    }

    if (tid < NOUT) {
        int ki = keep[tid];
        out[tid * 2 + 0] = probs[(size_t)ki * 2 + 0];
        out[tid * 2 + 1] = probs[(size_t)ki * 2 + 1];
        out[2 * NOUT + tid * 4 + 0] = boxes[(size_t)ki * 4 + 0];
        out[2 * NOUT + tid * 4 + 1] = boxes[(size_t)ki * 4 + 1];
        out[2 * NOUT + tid * 4 + 2] = boxes[(size_t)ki * 4 + 2];
        out[2 * NOUT + tid * 4 + 3] = boxes[(size_t)ki * 4 + 3];
    }
}

// ---------------------------------------------------------------------------
extern "C" void kernel_launch(void* const* d_in, const int* in_sizes, int n_in,
                              void* d_out, int out_size, void* d_ws, size_t ws_size,
                              hipStream_t stream)
{
    const float* x          = (const float*)d_in[0];
    const float* w_win      = (const float*)d_in[1];
    const float* b_win      = (const float*)d_in[2];
    const float* w_cls      = (const float*)d_in[3];
    const float* b_cls      = (const float*)d_in[4];
    const float* w_reg      = (const float*)d_in[5];
    const float* b_reg      = (const float*)d_in[6];
    const float* anchors_wh = (const float*)d_in[7];

    char* wsb = (char*)d_ws;
    float*     part      = (float*)(wsb);                 // 16,777,216 B [8][1024][512]
    float*     boxes     = (float*)(wsb + 16777216);      //    147,456 B
    float*     probs     = (float*)(wsb + 16924672);      //     73,728 B
    _Float16*  xp_hi     = (_Float16*)(wsb + 16998400);   //  1,183,744 B
    _Float16*  xp_lo     = (_Float16*)(wsb + 18182144);   //  1,183,744 B
    _Float16*  wt_hi     = (_Float16*)(wsb + 19365888);   //  4,718,592 B
    _Float16*  wt_lo     = (_Float16*)(wsb + 24084480);   //  4,718,592 B
    float*     wt_head   = (float*)(wsb + 28803072);      //    131,072 B [512][64]
    float*     bias_head = (float*)(wsb + 28934144);      //        256 B (end ~28.9 MB)

    prep_kernel<<<1196, 256, 0, stream>>>(x, w_win, w_cls, b_cls, w_reg, b_reg,
                                          xp_hi, xp_lo, wt_hi, wt_lo,
                                          wt_head, bias_head);
    conv_gemm_kernel<<<256, 256, 0, stream>>>(xp_hi, xp_lo, wt_hi, wt_lo, part);
    head_kernel<<<NPIX, 64, 0, stream>>>(part, b_win, wt_head, bias_head,
                                         anchors_wh, boxes, probs);
    nms_kernel<<<1, 1024, 0, stream>>>(boxes, probs, (float*)d_out);
}